// Round 7
// baseline (218.479 us; speedup 1.0000x reference)
//
#include <hip/hip_runtime.h>
#include <hip/hip_bf16.h>

#define N_ROWS 8192
#define N_HALF 4096
#define DIM    2048
#define INV_T  2.0f   // 1/TEMP, TEMP=0.5
#define NB     64     // 8192 / 128
#define NTRI   2080   // NB*(NB+1)/2
#define NPH    64     // DIM / 32 K-phases

typedef __attribute__((ext_vector_type(8))) short bf16x8;
typedef __attribute__((ext_vector_type(4))) float f32x4;

__device__ __forceinline__ float bf2f(short s) {
  return __uint_as_float(((unsigned int)(unsigned short)s) << 16);
}

__device__ __forceinline__ short f2bf(float x) {
  unsigned int u = __float_as_uint(x);
  u += 0x7fffu + ((u >> 16) & 1u);
  return (short)(u >> 16);
}

__device__ __forceinline__ void gload_lds16(const void* g, void* l) {
  __builtin_amdgcn_global_load_lds(
      (const __attribute__((address_space(1))) unsigned int*)g,
      (__attribute__((address_space(3))) unsigned int*)l, 16, 0, 0);
}

// ---------------------------------------------------------------------------
// Kernel 1: L2-normalize rows of x_i / x_j, write bf16 z (8192 x 2048)
// ---------------------------------------------------------------------------
__global__ __launch_bounds__(256) void normalize_k(
    const float* __restrict__ xi, const float* __restrict__ xj,
    short* __restrict__ z)
{
  const int row = blockIdx.x;
  const int t   = threadIdx.x;
  const float* src = (row < N_HALF) ? (xi + (size_t)row * DIM)
                                    : (xj + (size_t)(row - N_HALF) * DIM);
  const float4* src4 = (const float4*)src;
  float4 v0 = src4[t * 2];
  float4 v1 = src4[t * 2 + 1];
  float ss = v0.x*v0.x + v0.y*v0.y + v0.z*v0.z + v0.w*v0.w
           + v1.x*v1.x + v1.y*v1.y + v1.z*v1.z + v1.w*v1.w;
  #pragma unroll
  for (int m = 1; m < 64; m <<= 1) ss += __shfl_xor(ss, m, 64);
  __shared__ float red[4];
  if ((t & 63) == 0) red[t >> 6] = ss;
  __syncthreads();
  float total = red[0] + red[1] + red[2] + red[3];
  float scale = 1.0f / fmaxf(sqrtf(total), 1e-12f);

  float f[8] = {v0.x, v0.y, v0.z, v0.w, v1.x, v1.y, v1.z, v1.w};
  bf16x8 pack;
  #pragma unroll
  for (int e = 0; e < 8; ++e) pack[e] = f2bf(f[e] * scale);
  *((bf16x8*)(z + (size_t)row * DIM) + t) = pack;
}

// ---------------------------------------------------------------------------
// Kernel 2: positives pos[i] = z_i . z_{i +/- N}, self[i] = z_i . z_i (bf16)
// ---------------------------------------------------------------------------
__global__ __launch_bounds__(256) void posself_k(
    const short* __restrict__ z, float* __restrict__ pos,
    float* __restrict__ selfd)
{
  const int i = blockIdx.x;
  const int j = (i < N_HALF) ? (i + N_HALF) : (i - N_HALF);
  const int t = threadIdx.x;
  const bf16x8 va = ((const bf16x8*)(z + (size_t)i * DIM))[t];
  const bf16x8 vb = ((const bf16x8*)(z + (size_t)j * DIM))[t];
  float sp = 0.f, ss = 0.f;
  #pragma unroll
  for (int e = 0; e < 8; ++e) {
    float fa = bf2f(va[e]), fb = bf2f(vb[e]);
    sp += fa * fb;
    ss += fa * fa;
  }
  #pragma unroll
  for (int m = 1; m < 64; m <<= 1) {
    sp += __shfl_xor(sp, m, 64);
    ss += __shfl_xor(ss, m, 64);
  }
  __shared__ float rp[4], rs[4];
  if ((t & 63) == 0) { rp[t >> 6] = sp; rs[t >> 6] = ss; }
  __syncthreads();
  if (t == 0) {
    pos[i]   = rp[0] + rp[1] + rp[2] + rp[3];
    selfd[i] = rs[0] + rs[1] + rs[2] + rs[3];
  }
}

// ---------------------------------------------------------------------------
// Kernel 3: symmetric fused sim-tile + exp row/col sums, 128x128 tiles,
// full symmetric triangle bi <= bj: 2080 blocks.  Off-diagonal tiles
// contribute row-sums (denom[bi rows]) AND col-sums (denom[bj rows]);
// diagonal tiles row-sums only (full 128x128 computed) — each (i,j) counted
// exactly once.  FULL K per block (K-split removed: exp of partial sims is
// wrong, round-5 lesson).
// 4 waves (2M x 2N), per-wave 64x64 (4x4 16x16x32 frags, 16 MFMA/phase).
// 3-slot LDS rotation (lead-2): A-slot 8 KiB, B-slot 8 KiB -> 48 KiB total,
// 3 blocks/CU (768 slots; 2080/768 -> 90% tail balance vs 69% before).
// STAGE = 4 gload_lds16; steady vmcnt(4); vmcnt(0) final phase.
// Swizzled LDS (involution on staging-source + ds_read, linear dest):
//   LDS row q=r>>1 (128 B), 16B slot s = ((r&1)*4 + k4) ^ (q&7).
// ---------------------------------------------------------------------------
__global__ __launch_bounds__(256, 3) void simexp_k(
    const short* __restrict__ z, float* __restrict__ denom)
{
  __shared__ char lds[49152];
  char* ldsA = lds;            // 3 x 8192
  char* ldsB = lds + 24576;    // 3 x 8192

  const int t    = threadIdx.x;
  const int wave = t >> 6, lane = t & 63;
  const int wr   = wave >> 1, wc = wave & 1;   // 2M x 2N wave grid

  // XCD-aware bijective swizzle (2080 = 8*260), then triangular decode
  const int bid = blockIdx.x;
  int rem = (bid & 7) * (NTRI / 8) + (bid >> 3);
  int bi = 0;
  while (rem >= NB - bi) { rem -= NB - bi; ++bi; }
  const int bj   = bi + rem;
  const int row0 = bi * 128;
  const int col0 = bj * 128;

  // staging source offsets (swizzle-inverse of linear LDS dest).
  // One gload call = 256 thr x 16B = 4 KiB = LDS rows q=0..31 = logical
  // rows 0..63; second call covers rows 64..127 at dest +4096.
  const int sq  = t >> 3;                     // LDS row within a 4 KiB call
  const int ss0 = (t & 7) ^ (sq & 7);         // unswizzled slot
  const int sr  = 2 * sq + (ss0 >> 2);        // logical row 0..63
  const int sk4 = ss0 & 3;                    // 16B k-chunk
  const short* zA = z + (size_t)(row0 + sr) * DIM + sk4 * 8;
  const short* zB = z + (size_t)(col0 + sr) * DIM + sk4 * 8;
  char* dA = ldsA + wave * 1024;              // wave-uniform LDS dest bases
  char* dB = ldsB + wave * 1024;

  // ds_read byte offsets (swizzled)
  int offA[4], offB[4];
  #pragma unroll
  for (int m = 0; m < 4; ++m) {
    int r = wr * 64 + m * 16 + (lane & 15);
    int q = r >> 1;
    int s = ((lane >> 4) + (r & 1) * 4) ^ (q & 7);
    offA[m] = q * 128 + s * 16;
  }
  #pragma unroll
  for (int n = 0; n < 4; ++n) {
    int r = wc * 64 + n * 16 + (lane & 15);
    int q = r >> 1;
    int s = ((lane >> 4) + (r & 1) * 4) ^ (q & 7);
    offB[n] = q * 128 + s * 16;
  }

  f32x4 acc[4][4] = {};

#define STAGE(kh, slot) do {                                   \
    const short* pa_ = zA + (kh) * 32;                         \
    const short* pb_ = zB + (kh) * 32;                         \
    char* da_ = dA + (slot) * 8192;                            \
    char* db_ = dB + (slot) * 8192;                            \
    gload_lds16(pa_,            da_);                          \
    gload_lds16(pa_ + 64 * DIM, da_ + 4096);                   \
    gload_lds16(pb_,            db_);                          \
    gload_lds16(pb_ + 64 * DIM, db_ + 4096);                   \
  } while (0)

  // prologue: lead-2
  STAGE(0, 0);
  STAGE(1, 1);

  int sl = 0;
  for (int p = 0; p < NPH; ++p) {
    if (p < NPH - 1) asm volatile("s_waitcnt vmcnt(4)" ::: "memory");
    else             asm volatile("s_waitcnt vmcnt(0)" ::: "memory");
    __builtin_amdgcn_s_barrier();
    __builtin_amdgcn_sched_barrier(0);

    const char* Ab = ldsA + sl * 8192;
    const char* Bb = ldsB + sl * 8192;
    bf16x8 a[4], b[4];
    #pragma unroll
    for (int m = 0; m < 4; ++m) a[m] = *(const bf16x8*)(Ab + offA[m]);
    #pragma unroll
    for (int n = 0; n < 4; ++n) b[n] = *(const bf16x8*)(Bb + offB[n]);

    if (p + 2 < NPH) {
      int s2 = sl + 2; if (s2 >= 3) s2 -= 3;   // slot (p+2)%3 == (p-1)%3
      STAGE(p + 2, s2);                        // its readers passed barrier p
    }

    __builtin_amdgcn_s_setprio(1);
    #pragma unroll
    for (int m = 0; m < 4; ++m)
      #pragma unroll
      for (int n = 0; n < 4; ++n)
        acc[m][n] = __builtin_amdgcn_mfma_f32_16x16x32_bf16(a[m], b[n],
                                                            acc[m][n], 0, 0, 0);
    __builtin_amdgcn_s_setprio(0);
    __builtin_amdgcn_sched_barrier(0);

    if (++sl >= 3) sl = 0;
  }
#undef STAGE

  // ---- epilogue ----
  #pragma unroll
  for (int m = 0; m < 4; ++m)
    #pragma unroll
    for (int n = 0; n < 4; ++n)
      #pragma unroll
      for (int r = 0; r < 4; ++r)
        acc[m][n][r] = __expf(acc[m][n][r] * INV_T);

  // row sums: C layout col = lane&15, row = (lane>>4)*4 + reg
  #pragma unroll
  for (int m = 0; m < 4; ++m) {
    #pragma unroll
    for (int r = 0; r < 4; ++r) {
      float s = acc[m][0][r] + acc[m][1][r] + acc[m][2][r] + acc[m][3][r];
      s += __shfl_xor(s, 1, 64);
      s += __shfl_xor(s, 2, 64);
      s += __shfl_xor(s, 4, 64);
      s += __shfl_xor(s, 8, 64);
      if ((lane & 15) == 0) {
        int grow = row0 + wr * 64 + m * 16 + (lane >> 4) * 4 + r;
        atomicAdd(&denom[grow], s);
      }
    }
  }

  // col sums (mirror-tile contribution) — off-diagonal tiles only
  if (bi != bj) {
    #pragma unroll
    for (int n = 0; n < 4; ++n) {
      float cs = 0.f;
      #pragma unroll
      for (int m = 0; m < 4; ++m)
        #pragma unroll
        for (int r = 0; r < 4; ++r)
          cs += acc[m][n][r];
      cs += __shfl_xor(cs, 16, 64);
      cs += __shfl_xor(cs, 32, 64);
      if ((lane >> 4) == 0) {
        int gcol = col0 + wc * 64 + n * 16 + (lane & 15);
        atomicAdd(&denom[gcol], cs);
      }
    }
  }
}

// ---------------------------------------------------------------------------
// Kernel 4: loss = mean_i( log(denom_i - exp(self_i/T)) - pos_i/T )
// ---------------------------------------------------------------------------
__global__ __launch_bounds__(256) void loss_k(
    const float* __restrict__ denom, const float* __restrict__ pos,
    const float* __restrict__ selfd, float* __restrict__ out)
{
  const int t = threadIdx.x;
  float acc = 0.f;
  for (int i = t; i < N_ROWS; i += 256) {
    float d = denom[i] - __expf(selfd[i] * INV_T);
    acc += __logf(d) - pos[i] * INV_T;
  }
  #pragma unroll
  for (int m = 1; m < 64; m <<= 1) acc += __shfl_xor(acc, m, 64);
  __shared__ float red[4];
  if ((t & 63) == 0) red[t >> 6] = acc;
  __syncthreads();
  if (t == 0) out[0] = (red[0] + red[1] + red[2] + red[3]) / (float)N_ROWS;
}

// ---------------------------------------------------------------------------
extern "C" void kernel_launch(void* const* d_in, const int* in_sizes, int n_in,
                              void* d_out, int out_size, void* d_ws, size_t ws_size,
                              hipStream_t stream) {
  const float* xi = (const float*)d_in[0];
  const float* xj = (const float*)d_in[1];
  float* out = (float*)d_out;

  char*  ws    = (char*)d_ws;
  short* zb    = (short*)ws;                                   // 32 MiB bf16 z
  float* denom = (float*)(ws + (size_t)N_ROWS * DIM * 2);      // 8192 f32
  float* pos   = denom + N_ROWS;                               // 8192 f32
  float* selfd = pos + N_ROWS;                                 // 8192 f32

  hipMemsetAsync(denom, 0, N_ROWS * sizeof(float), stream);
  normalize_k<<<N_ROWS, 256, 0, stream>>>(xi, xj, zb);
  posself_k<<<N_ROWS, 256, 0, stream>>>(zb, pos, selfd);
  simexp_k<<<NTRI, 256, 0, stream>>>(zb, denom);
  loss_k<<<1, 256, 0, stream>>>(denom, pos, selfd, out);
}

// Round 8
// 208.262 us; speedup vs baseline: 1.0491x; 1.0491x over previous
//
#include <hip/hip_runtime.h>
#include <hip/hip_bf16.h>

#define N_ROWS 8192
#define N_HALF 4096
#define DIM    2048
#define INV_T  2.0f   // 1/TEMP, TEMP=0.5
#define NBJ    64     // 128-col blocks
#define NG1    1024   // grid1: sum_{bi}(63-2*bi)  (rightmost tile of each band carved out)
#define NG2    128    // grid2: 32 bands x 4 subtiles of 32 cols (cols 8064..8192)
#define NPH    64     // DIM / 32 K-phases

typedef __attribute__((ext_vector_type(8))) short bf16x8;
typedef __attribute__((ext_vector_type(4))) float f32x4;

__device__ __forceinline__ float bf2f(short s) {
  return __uint_as_float(((unsigned int)(unsigned short)s) << 16);
}

__device__ __forceinline__ short f2bf(float x) {
  unsigned int u = __float_as_uint(x);
  u += 0x7fffu + ((u >> 16) & 1u);
  return (short)(u >> 16);
}

__device__ __forceinline__ void gload_lds16(const void* g, void* l) {
  __builtin_amdgcn_global_load_lds(
      (const __attribute__((address_space(1))) unsigned int*)g,
      (__attribute__((address_space(3))) unsigned int*)l, 16, 0, 0);
}

// ---------------------------------------------------------------------------
// Kernel 1: L2-normalize rows of x_i / x_j, write bf16 z (8192 x 2048)
// ---------------------------------------------------------------------------
__global__ __launch_bounds__(256) void normalize_k(
    const float* __restrict__ xi, const float* __restrict__ xj,
    short* __restrict__ z)
{
  const int row = blockIdx.x;
  const int t   = threadIdx.x;
  const float* src = (row < N_HALF) ? (xi + (size_t)row * DIM)
                                    : (xj + (size_t)(row - N_HALF) * DIM);
  const float4* src4 = (const float4*)src;
  float4 v0 = src4[t * 2];
  float4 v1 = src4[t * 2 + 1];
  float ss = v0.x*v0.x + v0.y*v0.y + v0.z*v0.z + v0.w*v0.w
           + v1.x*v1.x + v1.y*v1.y + v1.z*v1.z + v1.w*v1.w;
  #pragma unroll
  for (int m = 1; m < 64; m <<= 1) ss += __shfl_xor(ss, m, 64);
  __shared__ float red[4];
  if ((t & 63) == 0) red[t >> 6] = ss;
  __syncthreads();
  float total = red[0] + red[1] + red[2] + red[3];
  float scale = 1.0f / fmaxf(sqrtf(total), 1e-12f);

  float f[8] = {v0.x, v0.y, v0.z, v0.w, v1.x, v1.y, v1.z, v1.w};
  bf16x8 pack;
  #pragma unroll
  for (int e = 0; e < 8; ++e) pack[e] = f2bf(f[e] * scale);
  *((bf16x8*)(z + (size_t)row * DIM) + t) = pack;
}

// ---------------------------------------------------------------------------
// Kernel 2: positives pos[i] = z_i . z_{i +/- N}, self[i] = z_i . z_i (bf16)
// ---------------------------------------------------------------------------
__global__ __launch_bounds__(256) void posself_k(
    const short* __restrict__ z, float* __restrict__ pos,
    float* __restrict__ selfd)
{
  const int i = blockIdx.x;
  const int j = (i < N_HALF) ? (i + N_HALF) : (i - N_HALF);
  const int t = threadIdx.x;
  const bf16x8 va = ((const bf16x8*)(z + (size_t)i * DIM))[t];
  const bf16x8 vb = ((const bf16x8*)(z + (size_t)j * DIM))[t];
  float sp = 0.f, ss = 0.f;
  #pragma unroll
  for (int e = 0; e < 8; ++e) {
    float fa = bf2f(va[e]), fb = bf2f(vb[e]);
    sp += fa * fb;
    ss += fa * fa;
  }
  #pragma unroll
  for (int m = 1; m < 64; m <<= 1) {
    sp += __shfl_xor(sp, m, 64);
    ss += __shfl_xor(ss, m, 64);
  }
  __shared__ float rp[4], rs[4];
  if ((t & 63) == 0) { rp[t >> 6] = sp; rs[t >> 6] = ss; }
  __syncthreads();
  if (t == 0) {
    pos[i]   = rp[0] + rp[1] + rp[2] + rp[3];
    selfd[i] = rs[0] + rs[1] + rs[2] + rs[3];
  }
}

// ---------------------------------------------------------------------------
// Kernel 3 (grid1): round-4 block verbatim — 256x128 tiles, 8 waves (4Mx2N),
// per-wave 128x64 (8x4 frags, 32 MFMA/phase, 43.7 FLOP/LDS-byte).
// Triangle bands bi (256 rows) x col-tiles bj in [2bi, 63) — the bj=63
// rightmost tile of every band is carved out to grid2 -> EXACTLY 1024
// blocks = 2 per CU-slot (2 blocks/CU, 512 slots): zero round-quantization.
// Row-sums always; col-sums iff bj >= 2bi+2.
// 3-slot LDS rotation lead-2 (A 16K + B 8K = 72 KiB), steady vmcnt(3).
// Swizzle: LDS row q=r>>1 (128 B), 16B slot s = ((r&1)*4 + k4) ^ (q&7),
// staged via inverse-swizzled global source (linear gload dest).
// ---------------------------------------------------------------------------
__global__ __launch_bounds__(512, 4) void simexp_k(
    const short* __restrict__ z, float* __restrict__ denom)
{
  __shared__ char lds[73728];
  char* ldsA = lds;            // 3 x 16384
  char* ldsB = lds + 49152;    // 3 x 8192

  const int t    = threadIdx.x;
  const int wave = t >> 6, lane = t & 63;
  const int wr   = wave >> 1, wc = wave & 1;   // 4M x 2N wave grid

  // XCD-aware bijective swizzle (1024 = 8*128), then band decode
  const int bid = blockIdx.x;
  int rem = (bid & 7) * (NG1 / 8) + (bid >> 3);
  int bi = 0;
  while (rem >= 63 - 2 * bi) { rem -= 63 - 2 * bi; ++bi; }
  const int bj   = 2 * bi + rem;               // in [2bi, 63)
  const int row0 = bi * 256;
  const int col0 = bj * 128;

  // staging source offsets (swizzle-inverse of linear LDS dest)
  const int sq  = t >> 3;                     // LDS row within an 8 KiB call
  const int ss0 = (t & 7) ^ (sq & 7);         // unswizzled slot
  const int sr  = 2 * sq + (ss0 >> 2);        // logical row 0..127
  const int sk4 = ss0 & 3;                    // 16B k-chunk
  const short* zA = z + (size_t)(row0 + sr) * DIM + sk4 * 8;
  const short* zB = z + (size_t)(col0 + sr) * DIM + sk4 * 8;
  char* dA = ldsA + wave * 1024;              // wave-uniform LDS dest bases
  char* dB = ldsB + wave * 1024;

  // ds_read byte offsets (swizzled)
  int offA[4], offB[4];
  #pragma unroll
  for (int m = 0; m < 4; ++m) {
    int r = wr * 64 + m * 16 + (lane & 15);
    int q = r >> 1;
    int s = ((lane >> 4) + (r & 1) * 4) ^ (q & 7);
    offA[m] = q * 128 + s * 16;
  }
  #pragma unroll
  for (int n = 0; n < 4; ++n) {
    int r = wc * 64 + n * 16 + (lane & 15);
    int q = r >> 1;
    int s = ((lane >> 4) + (r & 1) * 4) ^ (q & 7);
    offB[n] = q * 128 + s * 16;
  }

  f32x4 acc[4][4] = {};

#define STAGE(kh, slot) do {                                   \
    const short* pa_ = zA + (kh) * 32;                         \
    const short* pb_ = zB + (kh) * 32;                         \
    char* da_ = dA + (slot) * 16384;                           \
    char* db_ = dB + (slot) * 8192;                            \
    gload_lds16(pa_,             da_);                         \
    gload_lds16(pa_ + 128 * DIM, da_ + 8192);                  \
    gload_lds16(pb_,             db_);                         \
  } while (0)

  // prologue: lead-2
  STAGE(0, 0);
  STAGE(1, 1);

  int sl = 0;
  for (int p = 0; p < NPH; ++p) {
    if (p < NPH - 1) asm volatile("s_waitcnt vmcnt(3)" ::: "memory");
    else             asm volatile("s_waitcnt vmcnt(0)" ::: "memory");
    __builtin_amdgcn_s_barrier();
    __builtin_amdgcn_sched_barrier(0);

    const char* Ab = ldsA + sl * 16384;
    const char* Bb = ldsB + sl * 8192;
    bf16x8 a[4], b[4];
    #pragma unroll
    for (int m = 0; m < 4; ++m) a[m] = *(const bf16x8*)(Ab + offA[m]);
    #pragma unroll
    for (int n = 0; n < 4; ++n) b[n] = *(const bf16x8*)(Bb + offB[n]);

    if (p + 2 < NPH) {
      int s2 = sl + 2; if (s2 >= 3) s2 -= 3;   // slot (p+2)%3 == (p-1)%3
      STAGE(p + 2, s2);                        // its readers passed barrier p
    }

    __builtin_amdgcn_s_setprio(1);
    #pragma unroll
    for (int m = 0; m < 4; ++m)
      #pragma unroll
      for (int n = 0; n < 4; ++n)
        acc[m][n] = __builtin_amdgcn_mfma_f32_16x16x32_bf16(a[m], b[n],
                                                            acc[m][n], 0, 0, 0);
    __builtin_amdgcn_s_setprio(0);
    __builtin_amdgcn_sched_barrier(0);

    if (++sl >= 3) sl = 0;
  }
#undef STAGE

  // ---- epilogue ----
  #pragma unroll
  for (int m = 0; m < 4; ++m)
    #pragma unroll
    for (int n = 0; n < 4; ++n)
      #pragma unroll
      for (int r = 0; r < 4; ++r)
        acc[m][n][r] = __expf(acc[m][n][r] * INV_T);

  // row sums: C layout col = lane&15, row = (lane>>4)*4 + reg
  #pragma unroll
  for (int m = 0; m < 4; ++m) {
    #pragma unroll
    for (int r = 0; r < 4; ++r) {
      float s = acc[m][0][r] + acc[m][1][r] + acc[m][2][r] + acc[m][3][r];
      s += __shfl_xor(s, 1, 64);
      s += __shfl_xor(s, 2, 64);
      s += __shfl_xor(s, 4, 64);
      s += __shfl_xor(s, 8, 64);
      if ((lane & 15) == 0) {
        int grow = row0 + wr * 64 + m * 16 + (lane >> 4) * 4 + r;
        atomicAdd(&denom[grow], s);
      }
    }
  }

  // col sums (mirror-tile contribution) — only tiles right of diag block
  if (bj >= 2 * bi + 2) {
    #pragma unroll
    for (int n = 0; n < 4; ++n) {
      float cs = 0.f;
      #pragma unroll
      for (int m = 0; m < 4; ++m)
        #pragma unroll
        for (int r = 0; r < 4; ++r)
          cs += acc[m][n][r];
      cs += __shfl_xor(cs, 16, 64);
      cs += __shfl_xor(cs, 32, 64);
      if ((lane >> 4) == 0) {
        int gcol = col0 + wc * 64 + n * 16 + (lane & 15);
        atomicAdd(&denom[gcol], cs);
      }
    }
  }
}

// ---------------------------------------------------------------------------
// Kernel 3b (grid2): the carved-out strip — 256x32 tiles, cols 8064..8192.
// 128 blocks (32 bands x 4 subtiles).  Same schedule; NF=1 B-frag/wave.
// B slot = 32 rows x 32 k = 2 KiB, staged by waves 0-1 only (wave-guarded
// gload, per-wave vmcnt counts differ: waves 0-1 have 3 loads/stage, others
// 2).  Col-sums iff bi < 31 (strip right of diag block for those bands).
// ---------------------------------------------------------------------------
__global__ __launch_bounds__(512, 4) void simexp_narrow_k(
    const short* __restrict__ z, float* __restrict__ denom)
{
  __shared__ char lds[55296];
  char* ldsA = lds;            // 3 x 16384
  char* ldsB = lds + 49152;    // 3 x 2048

  const int t    = threadIdx.x;
  const int wave = t >> 6, lane = t & 63;
  const int wr   = wave >> 1, wc = wave & 1;   // 4M x 2N wave grid

  const int bid  = blockIdx.x;                 // 128 blocks, no swizzle needed
  const int bi   = bid >> 2;
  const int row0 = bi * 256;
  const int col0 = 8064 + (bid & 3) * 32;

  // staging source offsets: A (512 thr, rows 0..127 per call)
  const int sq  = t >> 3;
  const int ss0 = (t & 7) ^ (sq & 7);
  const int sr  = 2 * sq + (ss0 >> 2);
  const int sk4 = ss0 & 3;
  const short* zA = z + (size_t)(row0 + sr) * DIM + sk4 * 8;
  // B: waves 0-1 (t in 0..127), rows 0..31 of the 32-row col-strip
  const int sqB  = (t & 127) >> 3;             // 0..15
  const int ss0B = (t & 7) ^ (sqB & 7);
  const int srB  = 2 * sqB + (ss0B >> 2);      // 0..31
  const int sk4B = ss0B & 3;
  const short* zB = z + (size_t)(col0 + srB) * DIM + sk4B * 8;
  char* dA = ldsA + wave * 1024;
  char* dB = ldsB + wave * 1024;               // only waves 0,1 use it

  int offA[4], offB0;
  #pragma unroll
  for (int m = 0; m < 4; ++m) {
    int r = wr * 64 + m * 16 + (lane & 15);
    int q = r >> 1;
    int s = ((lane >> 4) + (r & 1) * 4) ^ (q & 7);
    offA[m] = q * 128 + s * 16;
  }
  {
    int r = wc * 16 + (lane & 15);             // 0..31
    int q = r >> 1;
    int s = ((lane >> 4) + (r & 1) * 4) ^ (q & 7);
    offB0 = q * 128 + s * 16;
  }

  f32x4 acc[4] = {};

#define STAGE(kh, slot) do {                                   \
    const short* pa_ = zA + (kh) * 32;                         \
    char* da_ = dA + (slot) * 16384;                           \
    gload_lds16(pa_,             da_);                         \
    gload_lds16(pa_ + 128 * DIM, da_ + 8192);                  \
    if (wave < 2)                                              \
      gload_lds16(zB + (kh) * 32, dB + (slot) * 2048);         \
  } while (0)

  STAGE(0, 0);
  STAGE(1, 1);

  int sl = 0;
  for (int p = 0; p < NPH; ++p) {
    if (p < NPH - 1) {
      if (wave < 2) asm volatile("s_waitcnt vmcnt(3)" ::: "memory");
      else          asm volatile("s_waitcnt vmcnt(2)" ::: "memory");
    } else {
      asm volatile("s_waitcnt vmcnt(0)" ::: "memory");
    }
    __builtin_amdgcn_s_barrier();
    __builtin_amdgcn_sched_barrier(0);

    const char* Ab = ldsA + sl * 16384;
    const char* Bb = ldsB + sl * 2048;
    bf16x8 a[4], b0;
    #pragma unroll
    for (int m = 0; m < 4; ++m) a[m] = *(const bf16x8*)(Ab + offA[m]);
    b0 = *(const bf16x8*)(Bb + offB0);

    if (p + 2 < NPH) {
      int s2 = sl + 2; if (s2 >= 3) s2 -= 3;
      STAGE(p + 2, s2);
    }

    __builtin_amdgcn_s_setprio(1);
    #pragma unroll
    for (int m = 0; m < 4; ++m)
      acc[m] = __builtin_amdgcn_mfma_f32_16x16x32_bf16(a[m], b0, acc[m], 0, 0, 0);
    __builtin_amdgcn_s_setprio(0);
    __builtin_amdgcn_sched_barrier(0);

    if (++sl >= 3) sl = 0;
  }
#undef STAGE

  #pragma unroll
  for (int m = 0; m < 4; ++m)
    #pragma unroll
    for (int r = 0; r < 4; ++r)
      acc[m][r] = __expf(acc[m][r] * INV_T);

  // row sums (16 cols per wave)
  #pragma unroll
  for (int m = 0; m < 4; ++m) {
    #pragma unroll
    for (int r = 0; r < 4; ++r) {
      float s = acc[m][r];
      s += __shfl_xor(s, 1, 64);
      s += __shfl_xor(s, 2, 64);
      s += __shfl_xor(s, 4, 64);
      s += __shfl_xor(s, 8, 64);
      if ((lane & 15) == 0) {
        int grow = row0 + wr * 64 + m * 16 + (lane >> 4) * 4 + r;
        atomicAdd(&denom[grow], s);
      }
    }
  }

  // col sums — strip is right of band-diag block for bi < 31
  if (bi < 31) {
    float cs = 0.f;
    #pragma unroll
    for (int m = 0; m < 4; ++m)
      #pragma unroll
      for (int r = 0; r < 4; ++r)
        cs += acc[m][r];
    cs += __shfl_xor(cs, 16, 64);
    cs += __shfl_xor(cs, 32, 64);
    if ((lane >> 4) == 0) {
      int gcol = col0 + wc * 16 + (lane & 15);
      atomicAdd(&denom[gcol], cs);
    }
  }
}

// ---------------------------------------------------------------------------
// Kernel 4: loss = mean_i( log(denom_i - exp(self_i/T)) - pos_i/T )
// ---------------------------------------------------------------------------
__global__ __launch_bounds__(256) void loss_k(
    const float* __restrict__ denom, const float* __restrict__ pos,
    const float* __restrict__ selfd, float* __restrict__ out)
{
  const int t = threadIdx.x;
  float acc = 0.f;
  for (int i = t; i < N_ROWS; i += 256) {
    float d = denom[i] - __expf(selfd[i] * INV_T);
    acc += __logf(d) - pos[i] * INV_T;
  }
  #pragma unroll
  for (int m = 1; m < 64; m <<= 1) acc += __shfl_xor(acc, m, 64);
  __shared__ float red[4];
  if ((t & 63) == 0) red[t >> 6] = acc;
  __syncthreads();
  if (t == 0) out[0] = (red[0] + red[1] + red[2] + red[3]) / (float)N_ROWS;
}

// ---------------------------------------------------------------------------
extern "C" void kernel_launch(void* const* d_in, const int* in_sizes, int n_in,
                              void* d_out, int out_size, void* d_ws, size_t ws_size,
                              hipStream_t stream) {
  const float* xi = (const float*)d_in[0];
  const float* xj = (const float*)d_in[1];
  float* out = (float*)d_out;

  char*  ws    = (char*)d_ws;
  short* zb    = (short*)ws;                                   // 32 MiB bf16 z
  float* denom = (float*)(ws + (size_t)N_ROWS * DIM * 2);      // 8192 f32
  float* pos   = denom + N_ROWS;                               // 8192 f32
  float* selfd = pos + N_ROWS;                                 // 8192 f32

  hipMemsetAsync(denom, 0, N_ROWS * sizeof(float), stream);
  normalize_k<<<N_ROWS, 256, 0, stream>>>(xi, xj, zb);
  posself_k<<<N_ROWS, 256, 0, stream>>>(zb, pos, selfd);
  simexp_k<<<NG1, 512, 0, stream>>>(zb, denom);
  simexp_narrow_k<<<NG2, 512, 0, stream>>>(zb, denom);
  loss_k<<<1, 256, 0, stream>>>(denom, pos, selfd, out);
}

// Round 9
// 183.508 us; speedup vs baseline: 1.1906x; 1.1349x over previous
//
#include <hip/hip_runtime.h>
#include <hip/hip_bf16.h>

#define N_ROWS 8192
#define N_HALF 4096
#define DIM    2048
#define INV_T  2.0f   // 1/TEMP, TEMP=0.5
#define NG1    1024   // full tiles: sum_{bi}(63-2*bi), bj in [2bi, 63)
#define NG2    256    // tail: 32 tiles (bj=63) M-split x8 (32-row blocks)
#define NPH    64     // DIM / 32 K-phases

typedef __attribute__((ext_vector_type(8))) short bf16x8;
typedef __attribute__((ext_vector_type(4))) float f32x4;

__device__ __forceinline__ float bf2f(short s) {
  return __uint_as_float(((unsigned int)(unsigned short)s) << 16);
}

__device__ __forceinline__ short f2bf(float x) {
  unsigned int u = __float_as_uint(x);
  u += 0x7fffu + ((u >> 16) & 1u);
  return (short)(u >> 16);
}

__device__ __forceinline__ void gload_lds16(const void* g, void* l) {
  __builtin_amdgcn_global_load_lds(
      (const __attribute__((address_space(1))) unsigned int*)g,
      (__attribute__((address_space(3))) unsigned int*)l, 16, 0, 0);
}

// ---------------------------------------------------------------------------
// Kernel 1: fused normalize + positives + self-dots.
// Block b handles paired rows (b, b+4096).  Normalizes both (fp32), writes
// bf16 z rows, then computes pos = z_b . z_{b+4096} and self-dots from the
// QUANTIZED bf16 values (matches what the MFMA diagonal computes).
// ---------------------------------------------------------------------------
__global__ __launch_bounds__(256) void normpos_k(
    const float* __restrict__ xi, const float* __restrict__ xj,
    short* __restrict__ z, float* __restrict__ pos,
    float* __restrict__ selfd)
{
  const int b = blockIdx.x;            // 0..4095
  const int t = threadIdx.x;
  const float4* si = (const float4*)(xi + (size_t)b * DIM);
  const float4* sj = (const float4*)(xj + (size_t)b * DIM);
  float4 a0 = si[t * 2], a1 = si[t * 2 + 1];
  float4 c0 = sj[t * 2], c1 = sj[t * 2 + 1];
  float ssi = a0.x*a0.x + a0.y*a0.y + a0.z*a0.z + a0.w*a0.w
            + a1.x*a1.x + a1.y*a1.y + a1.z*a1.z + a1.w*a1.w;
  float ssj = c0.x*c0.x + c0.y*c0.y + c0.z*c0.z + c0.w*c0.w
            + c1.x*c1.x + c1.y*c1.y + c1.z*c1.z + c1.w*c1.w;
  #pragma unroll
  for (int m = 1; m < 64; m <<= 1) {
    ssi += __shfl_xor(ssi, m, 64);
    ssj += __shfl_xor(ssj, m, 64);
  }
  __shared__ float ri[4], rj[4];
  if ((t & 63) == 0) { ri[t >> 6] = ssi; rj[t >> 6] = ssj; }
  __syncthreads();
  float sci = 1.0f / fmaxf(sqrtf(ri[0] + ri[1] + ri[2] + ri[3]), 1e-12f);
  float scj = 1.0f / fmaxf(sqrtf(rj[0] + rj[1] + rj[2] + rj[3]), 1e-12f);

  float fi[8] = {a0.x, a0.y, a0.z, a0.w, a1.x, a1.y, a1.z, a1.w};
  float fj[8] = {c0.x, c0.y, c0.z, c0.w, c1.x, c1.y, c1.z, c1.w};
  bf16x8 pi, pj;
  float dp = 0.f, dsi = 0.f, dsj = 0.f;
  #pragma unroll
  for (int e = 0; e < 8; ++e) {
    short qi = f2bf(fi[e] * sci), qj = f2bf(fj[e] * scj);
    pi[e] = qi; pj[e] = qj;
    float vi = bf2f(qi), vj = bf2f(qj);
    dp  += vi * vj;
    dsi += vi * vi;
    dsj += vj * vj;
  }
  *((bf16x8*)(z + (size_t)b * DIM) + t)            = pi;
  *((bf16x8*)(z + (size_t)(b + N_HALF) * DIM) + t) = pj;

  #pragma unroll
  for (int m = 1; m < 64; m <<= 1) {
    dp  += __shfl_xor(dp, m, 64);
    dsi += __shfl_xor(dsi, m, 64);
    dsj += __shfl_xor(dsj, m, 64);
  }
  __shared__ float rp[4], rsi[4], rsj[4];
  if ((t & 63) == 0) { rp[t >> 6] = dp; rsi[t >> 6] = dsi; rsj[t >> 6] = dsj; }
  __syncthreads();
  if (t == 0) {
    float p = rp[0] + rp[1] + rp[2] + rp[3];
    pos[b]           = p;
    pos[b + N_HALF]  = p;
    selfd[b]          = rsi[0] + rsi[1] + rsi[2] + rsi[3];
    selfd[b + N_HALF] = rsj[0] + rsj[1] + rsj[2] + rsj[3];
  }
}

// ---------------------------------------------------------------------------
// Kernel 2: symmetric fused sim-tile + exp row/col sums.  UNIFIED dispatch:
//  bids [0,1024): full 256x128 tiles, triangle bands bi x bj in [2bi,63)
//    = exactly 1024 blocks = 2 per CU-slot (2 blocks/CU): clean 2 rounds.
//  bids [1024,1280): tail — the 32 bj=63 tiles M-split x8 into 32-row
//    blocks (full K per block: M-split is exp-legal, K-split is NOT).
//    They dispatch last and fill CUs as the full blocks drain.
// Full path: 8 waves (4Mx2N), per-wave 64x64 (acc[4][4], 16 MFMA/phase).
// 3-slot LDS rotation lead-2 (A 16K + B 8K), steady vmcnt(3).
// Tail path: A-stage 2 KiB (waves 0-1 only; per-wave vmcnt asymmetry as in
// verified round-8 narrow), B-stage identical 8 KiB, acc[2] per wave.
// Swizzle (both sides, linear gload dest): LDS row q=r>>1 (128 B),
// 16B slot s = ((r&1)*4 + k4) ^ (q&7).
// Row-sums always; col-sums iff tile right of band diag (full: bj>=2bi+2,
// tail: bi<=30).  Diagonal exp(self) subtracted later in loss_k.
// ---------------------------------------------------------------------------
__global__ __launch_bounds__(512, 4) void simexp_k(
    const short* __restrict__ z, float* __restrict__ denom)
{
  __shared__ char lds[73728];
  char* ldsA = lds;            // 3 x 16384
  char* ldsB = lds + 49152;    // 3 x 8192

  const int t    = threadIdx.x;
  const int wave = t >> 6, lane = t & 63;
  const int bid  = blockIdx.x;

  if (bid < NG1) {
    // ===================== FULL TILE PATH (round-8 verbatim) ==============
    const int wr = wave >> 1, wc = wave & 1;   // 4M x 2N wave grid

    int rem = (bid & 7) * (NG1 / 8) + (bid >> 3);   // XCD-bijective swizzle
    int bi = 0;
    while (rem >= 63 - 2 * bi) { rem -= 63 - 2 * bi; ++bi; }
    const int bj   = 2 * bi + rem;               // in [2bi, 63)
    const int row0 = bi * 256;
    const int col0 = bj * 128;

    const int sq  = t >> 3;
    const int ss0 = (t & 7) ^ (sq & 7);
    const int sr  = 2 * sq + (ss0 >> 2);
    const int sk4 = ss0 & 3;
    const short* zA = z + (size_t)(row0 + sr) * DIM + sk4 * 8;
    const short* zB = z + (size_t)(col0 + sr) * DIM + sk4 * 8;
    char* dA = ldsA + wave * 1024;
    char* dB = ldsB + wave * 1024;

    int offA[4], offB[4];
    #pragma unroll
    for (int m = 0; m < 4; ++m) {
      int r = wr * 64 + m * 16 + (lane & 15);
      int q = r >> 1;
      int s = ((lane >> 4) + (r & 1) * 4) ^ (q & 7);
      offA[m] = q * 128 + s * 16;
    }
    #pragma unroll
    for (int n = 0; n < 4; ++n) {
      int r = wc * 64 + n * 16 + (lane & 15);
      int q = r >> 1;
      int s = ((lane >> 4) + (r & 1) * 4) ^ (q & 7);
      offB[n] = q * 128 + s * 16;
    }

    f32x4 acc[4][4] = {};

#define STAGE(kh, slot) do {                                   \
      const short* pa_ = zA + (kh) * 32;                       \
      const short* pb_ = zB + (kh) * 32;                       \
      char* da_ = dA + (slot) * 16384;                         \
      char* db_ = dB + (slot) * 8192;                          \
      gload_lds16(pa_,             da_);                       \
      gload_lds16(pa_ + 128 * DIM, da_ + 8192);                \
      gload_lds16(pb_,             db_);                       \
    } while (0)

    STAGE(0, 0);
    STAGE(1, 1);

    int sl = 0;
    for (int p = 0; p < NPH; ++p) {
      if (p < NPH - 1) asm volatile("s_waitcnt vmcnt(3)" ::: "memory");
      else             asm volatile("s_waitcnt vmcnt(0)" ::: "memory");
      __builtin_amdgcn_s_barrier();
      __builtin_amdgcn_sched_barrier(0);

      const char* Ab = ldsA + sl * 16384;
      const char* Bb = ldsB + sl * 8192;
      bf16x8 a[4], b[4];
      #pragma unroll
      for (int m = 0; m < 4; ++m) a[m] = *(const bf16x8*)(Ab + offA[m]);
      #pragma unroll
      for (int n = 0; n < 4; ++n) b[n] = *(const bf16x8*)(Bb + offB[n]);

      if (p + 2 < NPH) {
        int s2 = sl + 2; if (s2 >= 3) s2 -= 3;
        STAGE(p + 2, s2);
      }

      __builtin_amdgcn_s_setprio(1);
      #pragma unroll
      for (int m = 0; m < 4; ++m)
        #pragma unroll
        for (int n = 0; n < 4; ++n)
          acc[m][n] = __builtin_amdgcn_mfma_f32_16x16x32_bf16(a[m], b[n],
                                                              acc[m][n], 0, 0, 0);
      __builtin_amdgcn_s_setprio(0);
      __builtin_amdgcn_sched_barrier(0);

      if (++sl >= 3) sl = 0;
    }
#undef STAGE

    #pragma unroll
    for (int m = 0; m < 4; ++m)
      #pragma unroll
      for (int n = 0; n < 4; ++n)
        #pragma unroll
        for (int r = 0; r < 4; ++r)
          acc[m][n][r] = __expf(acc[m][n][r] * INV_T);

    #pragma unroll
    for (int m = 0; m < 4; ++m) {
      #pragma unroll
      for (int r = 0; r < 4; ++r) {
        float s = acc[m][0][r] + acc[m][1][r] + acc[m][2][r] + acc[m][3][r];
        s += __shfl_xor(s, 1, 64);
        s += __shfl_xor(s, 2, 64);
        s += __shfl_xor(s, 4, 64);
        s += __shfl_xor(s, 8, 64);
        if ((lane & 15) == 0) {
          int grow = row0 + wr * 64 + m * 16 + (lane >> 4) * 4 + r;
          atomicAdd(&denom[grow], s);
        }
      }
    }

    if (bj >= 2 * bi + 2) {
      #pragma unroll
      for (int n = 0; n < 4; ++n) {
        float cs = 0.f;
        #pragma unroll
        for (int m = 0; m < 4; ++m)
          #pragma unroll
          for (int r = 0; r < 4; ++r)
            cs += acc[m][n][r];
        cs += __shfl_xor(cs, 16, 64);
        cs += __shfl_xor(cs, 32, 64);
        if ((lane >> 4) == 0) {
          int gcol = col0 + wc * 64 + n * 16 + (lane & 15);
          atomicAdd(&denom[gcol], cs);
        }
      }
    }
  } else {
    // ===================== TAIL PATH: 32-row x 128-col, cols 8064.. =======
    const int sub  = bid - NG1;                // 0..255
    const int bi   = sub >> 3;                 // band 0..31
    const int row0 = bi * 256 + (sub & 7) * 32;
    const int col0 = 8064;

    // B staging: identical pattern to full path (128 strip cols)
    const int sq  = t >> 3;
    const int ss0 = (t & 7) ^ (sq & 7);
    const int sr  = 2 * sq + (ss0 >> 2);
    const int sk4 = ss0 & 3;
    const short* zB = z + (size_t)(col0 + sr) * DIM + sk4 * 8;
    // A staging: threads 0..127 (waves 0-1) cover the 32 rows (2 KiB)
    const int tA   = t & 127;
    const int sqA  = tA >> 3;                  // 0..15
    const int ss0A = (tA & 7) ^ (sqA & 7);
    const int srA  = 2 * sqA + (ss0A >> 2);    // 0..31
    const int sk4A = ss0A & 3;
    const short* zAs = z + (size_t)(row0 + srA) * DIM + sk4A * 8;
    char* dA = ldsA + wave * 1024;             // waves 0-1 only
    char* dB = ldsB + wave * 1024;

    int offA2[2], offB0;
    #pragma unroll
    for (int m = 0; m < 2; ++m) {
      int r = m * 16 + (lane & 15);            // 0..31
      int q = r >> 1;
      int s = ((lane >> 4) + (r & 1) * 4) ^ (q & 7);
      offA2[m] = q * 128 + s * 16;
    }
    {
      int r = wave * 16 + (lane & 15);         // 0..127
      int q = r >> 1;
      int s = ((lane >> 4) + (r & 1) * 4) ^ (q & 7);
      offB0 = q * 128 + s * 16;
    }

    f32x4 acc2[2] = {};

#define STAGE_T(kh, slot) do {                                 \
      gload_lds16(zB + (kh) * 32, dB + (slot) * 8192);         \
      if (wave < 2)                                            \
        gload_lds16(zAs + (kh) * 32, dA + (slot) * 16384);     \
    } while (0)

    STAGE_T(0, 0);
    STAGE_T(1, 1);

    int sl = 0;
    for (int p = 0; p < NPH; ++p) {
      if (p < NPH - 1) {
        if (wave < 2) asm volatile("s_waitcnt vmcnt(2)" ::: "memory");
        else          asm volatile("s_waitcnt vmcnt(1)" ::: "memory");
      } else {
        asm volatile("s_waitcnt vmcnt(0)" ::: "memory");
      }
      __builtin_amdgcn_s_barrier();
      __builtin_amdgcn_sched_barrier(0);

      const char* Ab = ldsA + sl * 16384;
      const char* Bb = ldsB + sl * 8192;
      bf16x8 a0 = *(const bf16x8*)(Ab + offA2[0]);
      bf16x8 a1 = *(const bf16x8*)(Ab + offA2[1]);
      bf16x8 b0 = *(const bf16x8*)(Bb + offB0);

      if (p + 2 < NPH) {
        int s2 = sl + 2; if (s2 >= 3) s2 -= 3;
        STAGE_T(p + 2, s2);
      }

      __builtin_amdgcn_s_setprio(1);
      acc2[0] = __builtin_amdgcn_mfma_f32_16x16x32_bf16(a0, b0, acc2[0], 0, 0, 0);
      acc2[1] = __builtin_amdgcn_mfma_f32_16x16x32_bf16(a1, b0, acc2[1], 0, 0, 0);
      __builtin_amdgcn_s_setprio(0);
      __builtin_amdgcn_sched_barrier(0);

      if (++sl >= 3) sl = 0;
    }
#undef STAGE_T

    #pragma unroll
    for (int m = 0; m < 2; ++m)
      #pragma unroll
      for (int r = 0; r < 4; ++r)
        acc2[m][r] = __expf(acc2[m][r] * INV_T);

    // row sums: each wave contributes its 16-col slice of rows row0..row0+31
    #pragma unroll
    for (int m = 0; m < 2; ++m) {
      #pragma unroll
      for (int r = 0; r < 4; ++r) {
        float s = acc2[m][r];
        s += __shfl_xor(s, 1, 64);
        s += __shfl_xor(s, 2, 64);
        s += __shfl_xor(s, 4, 64);
        s += __shfl_xor(s, 8, 64);
        if ((lane & 15) == 0) {
          int grow = row0 + m * 16 + (lane >> 4) * 4 + r;
          atomicAdd(&denom[grow], s);
        }
      }
    }

    // col sums (partial over 32 rows, accumulated across the 8 M-splits)
    if (bi <= 30) {     // band 31's bj=63 tile is in-band: row-sums cover it
      float cs = 0.f;
      #pragma unroll
      for (int m = 0; m < 2; ++m)
        #pragma unroll
        for (int r = 0; r < 4; ++r)
          cs += acc2[m][r];
      cs += __shfl_xor(cs, 16, 64);
      cs += __shfl_xor(cs, 32, 64);
      if ((lane >> 4) == 0) {
        int gcol = col0 + wave * 16 + (lane & 15);
        atomicAdd(&denom[gcol], cs);
      }
    }
  }
}

// ---------------------------------------------------------------------------
// Kernel 3: loss = mean_i( log(denom_i - exp(self_i/T)) - pos_i/T )
// ---------------------------------------------------------------------------
__global__ __launch_bounds__(256) void loss_k(
    const float* __restrict__ denom, const float* __restrict__ pos,
    const float* __restrict__ selfd, float* __restrict__ out)
{
  const int t = threadIdx.x;
  float acc = 0.f;
  for (int i = t; i < N_ROWS; i += 256) {
    float d = denom[i] - __expf(selfd[i] * INV_T);
    acc += __logf(d) - pos[i] * INV_T;
  }
  #pragma unroll
  for (int m = 1; m < 64; m <<= 1) acc += __shfl_xor(acc, m, 64);
  __shared__ float red[4];
  if ((t & 63) == 0) red[t >> 6] = acc;
  __syncthreads();
  if (t == 0) out[0] = (red[0] + red[1] + red[2] + red[3]) / (float)N_ROWS;
}

// ---------------------------------------------------------------------------
extern "C" void kernel_launch(void* const* d_in, const int* in_sizes, int n_in,
                              void* d_out, int out_size, void* d_ws, size_t ws_size,
                              hipStream_t stream) {
  const float* xi = (const float*)d_in[0];
  const float* xj = (const float*)d_in[1];
  float* out = (float*)d_out;

  char*  ws    = (char*)d_ws;
  short* zb    = (short*)ws;                                   // 32 MiB bf16 z
  float* denom = (float*)(ws + (size_t)N_ROWS * DIM * 2);      // 8192 f32
  float* pos   = denom + N_ROWS;                               // 8192 f32
  float* selfd = pos + N_ROWS;                                 // 8192 f32

  hipMemsetAsync(denom, 0, N_ROWS * sizeof(float), stream);
  normpos_k<<<N_HALF, 256, 0, stream>>>(xi, xj, zb, pos, selfd);
  simexp_k<<<NG1 + NG2, 512, 0, stream>>>(zb, denom);
  loss_k<<<1, 256, 0, stream>>>(denom, pos, selfd, out);
}